// Round 21
// baseline (284.647 us; speedup 1.0000x reference)
//
#include <hip/hip_runtime.h>

// ---------------------------------------------------------------------------
// IGCN link prediction, round 20 = R19 (276us) + bin-role parallelism fix:
// chunk 8192 -> 2048 (binblocks 391 -> 1563; bin was 1.5 blocks/CU after the
// gemm blocks drained -> latency-bound tail). Bin blocks ordered FIRST so the
// low-ILP binning starts at t=0 and gemm backfills.
// ---------------------------------------------------------------------------

constexpr int BKT_SHIFT = 7;     // 128 nodes per bucket
constexpr int BKT_NODES = 128;
constexpr int SORT_CAP  = 3584;  // records/bucket (mean 2048, +34 sigma)

typedef __attribute__((ext_vector_type(8))) short bf16x8;
typedef __attribute__((ext_vector_type(4))) float f32x4;

__device__ __forceinline__ float wave_sum64(float x) {
#pragma unroll
    for (int o = 32; o > 0; o >>= 1) x += __shfl_xor(x, o, 64);
    return x;
}

__device__ __forceinline__ unsigned short f2bf(float f) {  // round-nearest-even
    unsigned int u = __float_as_uint(f);
    u += 0x7FFF + ((u >> 16) & 1);
    return (unsigned short)(u >> 16);
}

__device__ __forceinline__ float2 bf2f2(unsigned int u) {  // 2 bf16 -> 2 f32
    float2 r;
    r.x = __uint_as_float(u << 16);
    r.y = __uint_as_float(u & 0xFFFF0000u);
    return r;
}

constexpr float VQ_INV = 1.0f / 32767.0f;

// ---------------- CSR bucket build: hist + scan ----------------

__global__ __launch_bounds__(256) void bhist_k(const int* __restrict__ eo,
                                               const int* __restrict__ es,
                                               int* __restrict__ bcnt,
                                               int E, int N, int nb) {
    __shared__ int lh[2048];
    for (int i = threadIdx.x; i < nb; i += 256) lh[i] = 0;
    __syncthreads();
    int total = 2 * E;
    for (int t = blockIdx.x * 256 + threadIdx.x; t < total; t += gridDim.x * 256) {
        int g = (t >= E) ? 1 : 0;
        int e = g ? t - E : t;
        int dst = (g ? es : eo)[e];
        atomicAdd(&lh[(g * N + dst) >> BKT_SHIFT], 1);
    }
    __syncthreads();
    for (int i = threadIdx.x; i < nb; i += 256) {
        int v = lh[i];
        if (v) atomicAdd(&bcnt[i], v);
    }
}

// scan up to 2048 bucket counts (2 elems/thread) -> bases + cursors
__global__ __launch_bounds__(1024) void bscan2_k(const int* __restrict__ bcnt,
                                                 int* __restrict__ bbase,
                                                 int* __restrict__ bcur,
                                                 int nb, int total) {
    __shared__ int sh[1024];
    int t = threadIdx.x;
    int i0 = 2 * t, i1 = 2 * t + 1;
    int v0 = (i0 < nb) ? bcnt[i0] : 0;
    int v1 = (i1 < nb) ? bcnt[i1] : 0;
    int p = v0 + v1;
    sh[t] = p;
    __syncthreads();
#pragma unroll
    for (int o = 1; o < 1024; o <<= 1) {
        int tv = (t >= o) ? sh[t - o] : 0;
        __syncthreads();
        sh[t] += tv;
        __syncthreads();
    }
    int excl = sh[t] - p;
    if (i0 < nb) { bbase[i0] = excl;      bcur[i0] = excl; }
    if (i1 < nb) { bbase[i1] = excl + v0; bcur[i1] = excl + v0; }
    if (t == 0) bbase[nb] = total;
}

// ---------------- fat-kernel roles (32KB smem) ----------------

__device__ __forceinline__ void bin_role(unsigned char* smem, int bb,
                                         const int* __restrict__ eo,
                                         const float* __restrict__ vo,
                                         const int* __restrict__ es,
                                         const float* __restrict__ vs,
                                         int* __restrict__ bcur,
                                         int2* __restrict__ binned,
                                         int E, int N, int nb, int chunk) {
    int* lcnt = (int*)smem;           // 2048 ints (8KB)
    int* lbase = lcnt + 2048;         // 2048 ints (8KB)
    int c0 = bb * chunk;
    int c1 = min(c0 + chunk, 2 * E);
    for (int i = threadIdx.x; i < nb; i += 256) lcnt[i] = 0;
    __syncthreads();
    for (int t = c0 + threadIdx.x; t < c1; t += 256) {
        int g = (t >= E) ? 1 : 0;
        int e = g ? t - E : t;
        int dst = (g ? es : eo)[e];
        atomicAdd(&lcnt[(g * N + dst) >> BKT_SHIFT], 1);
    }
    __syncthreads();
    for (int i = threadIdx.x; i < nb; i += 256) {
        int v = lcnt[i];
        lbase[i] = v ? atomicAdd(&bcur[i], v) : 0;
        lcnt[i] = 0;  // reuse as local cursor
    }
    __syncthreads();
    for (int t = c0 + threadIdx.x; t < c1; t += 256) {
        int g = (t >= E) ? 1 : 0;
        int e = g ? t - E : t;
        const int* edges = g ? es : eo;
        int dst = edges[e];
        int dc = g * N + dst;
        int b = dc >> BKT_SHIFT;
        int pos = lbase[b] + atomicAdd(&lcnt[b], 1);
        int src = edges[E + e];
        float val = (g ? vs : vo)[e];
        binned[pos] = make_int2(((dc & (BKT_NODES - 1)) << 17) | src,
                                __float_as_int(val));
    }
}

// gemm role: A-frags direct from global X (f32->bf16 in regs); only WT in LDS.
__device__ __forceinline__ void gemm_role(unsigned char* smem, int blk,
                                          const float* __restrict__ X,
                                          const float* __restrict__ W0,
                                          const float* __restrict__ W1,
                                          unsigned short* __restrict__ S0,
                                          unsigned short* __restrict__ S1,
                                          int nrows) {
    unsigned short* WT = (unsigned short*)smem;  // 32 KB

    const int tid = threadIdx.x;
    const int row0 = blk * 128;
    const int w4 = (tid >> 6) * 32;
    const int lr = tid & 15;
    const int kg = (tid >> 4) & 3;

    bf16x8 a[2][4];
#pragma unroll
    for (int rt = 0; rt < 2; ++rt) {
        int gr = row0 + w4 + rt * 16 + lr;
        if (gr >= nrows) gr = nrows - 1;  // clamp; stores guarded
        const float4* Xr = (const float4*)(X + (size_t)gr * 128);
#pragma unroll
        for (int kt = 0; kt < 4; ++kt) {
            float4 v0 = Xr[(kt * 4 + kg) * 2 + 0];
            float4 v1 = Xr[(kt * 4 + kg) * 2 + 1];
            union { unsigned short h[8]; bf16x8 v; } p;
            p.h[0] = f2bf(v0.x); p.h[1] = f2bf(v0.y);
            p.h[2] = f2bf(v0.z); p.h[3] = f2bf(v0.w);
            p.h[4] = f2bf(v1.x); p.h[5] = f2bf(v1.y);
            p.h[6] = f2bf(v1.z); p.h[7] = f2bf(v1.w);
            a[rt][kt] = p.v;
        }
    }

    for (int br = 0; br < 2; ++br) {
        const float* W = br ? W1 : W0;
        unsigned short* S = br ? S1 : S0;
        if (br) __syncthreads();
        {
            int c = tid >> 1;
            int kh = (tid & 1) * 64;
#pragma unroll 8
            for (int k2 = 0; k2 < 32; ++k2) {
                int k = kh + 2 * k2;
                unsigned int lo = f2bf(W[k * 128 + c]);
                unsigned int hi = f2bf(W[(k + 1) * 128 + c]);
                int bp = (k >> 3) ^ (c & 15);
                ((unsigned int*)&WT[c * 128 + bp * 8])[(k >> 1) & 3] = lo | (hi << 16);
            }
        }
        __syncthreads();

        f32x4 acc[2][8];
#pragma unroll
        for (int rt = 0; rt < 2; ++rt)
#pragma unroll
            for (int ct = 0; ct < 8; ++ct) acc[rt][ct] = (f32x4){0.f, 0.f, 0.f, 0.f};

#pragma unroll
        for (int ct = 0; ct < 8; ++ct) {
#pragma unroll
            for (int kt = 0; kt < 4; ++kt) {
                bf16x8 b = *(const bf16x8*)&WT[(ct * 16 + lr) * 128 +
                                               (((kt * 4 + kg) ^ lr) * 8)];
                acc[0][ct] = __builtin_amdgcn_mfma_f32_16x16x32_bf16(a[0][kt], b, acc[0][ct], 0, 0, 0);
                acc[1][ct] = __builtin_amdgcn_mfma_f32_16x16x32_bf16(a[1][kt], b, acc[1][ct], 0, 0, 0);
            }
        }

#pragma unroll
        for (int rt = 0; rt < 2; ++rt)
#pragma unroll
            for (int j = 0; j < 4; ++j) {
                int gr = row0 + w4 + rt * 16 + kg * 4 + j;
                if (gr < nrows) {
                    size_t rb = (size_t)gr * 128 + lr;
#pragma unroll
                    for (int ct = 0; ct < 8; ++ct)
                        S[rb + ct * 16] = f2bf(acc[rt][ct][j]);
                }
            }
    }
}

__device__ __forceinline__ void prep_role(unsigned char* smem,
                                          const float* __restrict__ dec1_W,
                                          const float* __restrict__ dec1_b,
                                          const float* __restrict__ dec2_W,
                                          const float* __restrict__ dec2_b,
                                          const float* __restrict__ W_o2,
                                          const float* __restrict__ b_o2,
                                          const float* __restrict__ W_s2,
                                          const float* __restrict__ b_s2,
                                          const float* __restrict__ ag1,
                                          const float* __restrict__ ag2,
                                          float* __restrict__ Mo,
                                          float* __restrict__ Ms,
                                          float* __restrict__ beta,
                                          float* __restrict__ cc) {
    float* vsh = (float*)smem;  // 128 floats
    int t = threadIdx.x;
    if (t < 128) {
        float s = 0.f;
        for (int j = 0; j < 64; ++j) s += dec1_W[t * 64 + j] * dec2_W[j];
        vsh[t] = s;
    }
    __syncthreads();
    if (t < 128) {
        const float* vlo = vsh;
        const float* vhi = vsh + 64;
        float m0 = 0, m1 = 0, m2 = 0, n0 = 0, n1 = 0, n2 = 0;
        for (int k = 0; k < 64; ++k) {
            float wo = W_o2[t * 64 + k], wsv = W_s2[t * 64 + k];
            m0 += wo * ag1[k];  m1 += wo * vlo[k];  m2 += wo * vhi[k];
            n0 += wsv * ag2[k]; n1 += wsv * vlo[k]; n2 += wsv * vhi[k];
        }
        Mo[0 * 128 + t] = m0; Mo[1 * 128 + t] = m1; Mo[2 * 128 + t] = m2;
        Ms[0 * 128 + t] = n0; Ms[1 * 128 + t] = n1; Ms[2 * 128 + t] = n2;
        if (t == 0) {
            float b0 = 0, b1 = 0, b2 = 0, s0 = 0, s1 = 0, s2 = 0, c0 = 0;
            for (int k = 0; k < 64; ++k) {
                b0 += b_o2[k] * ag1[k]; b1 += b_o2[k] * vlo[k]; b2 += b_o2[k] * vhi[k];
                s0 += b_s2[k] * ag2[k]; s1 += b_s2[k] * vlo[k]; s2 += b_s2[k] * vhi[k];
                c0 += dec1_b[k] * dec2_W[k];
            }
            beta[0] = b0; beta[1] = b1; beta[2] = b2;
            beta[4] = s0; beta[5] = s1; beta[6] = s2;
            *cc = c0 + dec2_b[0];
        }
    }
}

// fat kernel: BIN blocks first | gemm blocks | prep block
__global__ __launch_bounds__(256) void fused_k(
    int gblocks, int binblocks,
    const float* __restrict__ X, const float* __restrict__ W0,
    const float* __restrict__ W1, unsigned short* __restrict__ S0,
    unsigned short* __restrict__ S1, int nrows,
    const int* __restrict__ eo, const float* __restrict__ vo,
    const int* __restrict__ es, const float* __restrict__ vs,
    int* __restrict__ bcur, int2* __restrict__ binned,
    int E, int N, int nb, int chunk,
    const float* __restrict__ dec1_W, const float* __restrict__ dec1_b,
    const float* __restrict__ dec2_W, const float* __restrict__ dec2_b,
    const float* __restrict__ W_o2, const float* __restrict__ b_o2,
    const float* __restrict__ W_s2, const float* __restrict__ b_s2,
    const float* __restrict__ ag1, const float* __restrict__ ag2,
    float* __restrict__ Mo, float* __restrict__ Ms,
    float* __restrict__ beta, float* __restrict__ cc) {
    __shared__ __align__(16) unsigned char smem[32 * 1024];
    int bid = blockIdx.x;
    if (bid < binblocks) {
        bin_role(smem, bid, eo, vo, es, vs, bcur, binned, E, N, nb, chunk);
    } else if (bid < binblocks + gblocks) {
        gemm_role(smem, bid - binblocks, X, W0, W1, S0, S1, nrows);
    } else {
        prep_role(smem, dec1_W, dec1_b, dec2_W, dec2_b, W_o2, b_o2, W_s2, b_s2,
                  ag1, ag2, Mo, Ms, beta, cc);
    }
}

// ------ per-bucket sort: emits PACKED 4B csr records (q15<<17 | src) --------

__global__ __launch_bounds__(256) void sort_k(const int* __restrict__ bbase,
                                              const int2* __restrict__ binned,
                                              unsigned int* __restrict__ csr,
                                              int* __restrict__ rp2,
                                              int n2, int total) {
    __shared__ int2 lrec[SORT_CAP];
    __shared__ int ldeg[BKT_NODES];
    __shared__ int lsc[BKT_NODES];
    int b = blockIdx.x;
    int base = bbase[b];
    int count = min(bbase[b + 1] - base, SORT_CAP);
    int tid = threadIdx.x;
    for (int k = tid; k < count; k += 256) lrec[k] = binned[base + k];
    if (tid < BKT_NODES) ldeg[tid] = 0;
    __syncthreads();
    for (int k = tid; k < count; k += 256) atomicAdd(&ldeg[lrec[k].x >> 17], 1);
    __syncthreads();
    int v = 0;
    if (tid < BKT_NODES) {
        v = ldeg[tid];
        lsc[tid] = v;
    }
    __syncthreads();
#pragma unroll
    for (int o = 1; o < BKT_NODES; o <<= 1) {
        int tv = 0;
        if (tid < BKT_NODES) tv = (tid >= o) ? lsc[tid - o] : 0;
        __syncthreads();
        if (tid < BKT_NODES) lsc[tid] += tv;
        __syncthreads();
    }
    if (tid < BKT_NODES) {
        int excl = lsc[tid] - v;
        int node = b * BKT_NODES + tid;
        if (node < n2) rp2[node] = base + excl;
        ldeg[tid] = excl;  // reuse as scatter cursor
    }
    if (b == 0 && tid == 0) rp2[n2] = total;
    __syncthreads();
    for (int k = tid; k < count; k += 256) {
        int2 r = lrec[k];
        int dl = r.x >> 17;
        int p = atomicAdd(&ldeg[dl], 1);
        float val = __int_as_float(r.y);
        unsigned int q = (unsigned int)__float2uint_rn(val * 32767.0f);
        csr[base + p] = (q << 17) | (unsigned int)(r.x & 0x1FFFF);
    }
}

// ------- layer-1 gather SpMM (bf16 rows, packed 4B records) ------------------
__global__ __launch_bounds__(256) void seg_spmm_fused2_k(
    const int* __restrict__ rp2, const unsigned int* __restrict__ csr,
    const unsigned short* __restrict__ So, const unsigned short* __restrict__ Ss,
    const float* __restrict__ bias_o, const float* __restrict__ bias_s,
    const float* __restrict__ Mo, const float* __restrict__ Ms,
    float4* __restrict__ To, float4* __restrict__ Ts, int n) {
    const int* rp;
    const unsigned int* S;
    const float* bias;
    const float* M;
    float4* T;
    if (blockIdx.y == 0) {
        rp = rp2;     S = (const unsigned int*)So; bias = bias_o; M = Mo; T = To;
    } else {
        rp = rp2 + n; S = (const unsigned int*)Ss; bias = bias_s; M = Ms; T = Ts;
    }
    int wid = (blockIdx.x * 256 + threadIdx.x) >> 6;
    int lane = threadIdx.x & 63;
    if (wid >= n) return;
    int e = rp[wid], end = rp[wid + 1];
    float ax = 0.f, ay = 0.f;
    for (; e + 7 < end; e += 8) {
        unsigned int c0 = csr[e],     c1 = csr[e + 1], c2 = csr[e + 2], c3 = csr[e + 3];
        unsigned int c4 = csr[e + 4], c5 = csr[e + 5], c6 = csr[e + 6], c7 = csr[e + 7];
        float2 m0 = bf2f2(S[(c0 & 0x1FFFF) * 64 + lane]);
        float2 m1 = bf2f2(S[(c1 & 0x1FFFF) * 64 + lane]);
        float2 m2 = bf2f2(S[(c2 & 0x1FFFF) * 64 + lane]);
        float2 m3 = bf2f2(S[(c3 & 0x1FFFF) * 64 + lane]);
        float2 m4 = bf2f2(S[(c4 & 0x1FFFF) * 64 + lane]);
        float2 m5 = bf2f2(S[(c5 & 0x1FFFF) * 64 + lane]);
        float2 m6 = bf2f2(S[(c6 & 0x1FFFF) * 64 + lane]);
        float2 m7 = bf2f2(S[(c7 & 0x1FFFF) * 64 + lane]);
        float v0 = (float)(c0 >> 17) * VQ_INV, v1 = (float)(c1 >> 17) * VQ_INV;
        float v2 = (float)(c2 >> 17) * VQ_INV, v3 = (float)(c3 >> 17) * VQ_INV;
        float v4 = (float)(c4 >> 17) * VQ_INV, v5 = (float)(c5 >> 17) * VQ_INV;
        float v6 = (float)(c6 >> 17) * VQ_INV, v7 = (float)(c7 >> 17) * VQ_INV;
        ax += m0.x * v0 + m1.x * v1 + m2.x * v2 + m3.x * v3;
        ay += m0.y * v0 + m1.y * v1 + m2.y * v2 + m3.y * v3;
        ax += m4.x * v4 + m5.x * v5 + m6.x * v6 + m7.x * v7;
        ay += m4.y * v4 + m5.y * v5 + m6.y * v6 + m7.y * v7;
    }
    for (; e + 3 < end; e += 4) {
        unsigned int c0 = csr[e], c1 = csr[e + 1], c2 = csr[e + 2], c3 = csr[e + 3];
        float2 m0 = bf2f2(S[(c0 & 0x1FFFF) * 64 + lane]);
        float2 m1 = bf2f2(S[(c1 & 0x1FFFF) * 64 + lane]);
        float2 m2 = bf2f2(S[(c2 & 0x1FFFF) * 64 + lane]);
        float2 m3 = bf2f2(S[(c3 & 0x1FFFF) * 64 + lane]);
        float v0 = (float)(c0 >> 17) * VQ_INV, v1 = (float)(c1 >> 17) * VQ_INV;
        float v2 = (float)(c2 >> 17) * VQ_INV, v3 = (float)(c3 >> 17) * VQ_INV;
        ax += m0.x * v0 + m1.x * v1 + m2.x * v2 + m3.x * v3;
        ay += m0.y * v0 + m1.y * v1 + m2.y * v2 + m3.y * v3;
    }
    for (; e < end; ++e) {
        unsigned int c = csr[e];
        float2 m = bf2f2(S[(c & 0x1FFFF) * 64 + lane]);
        float v = (float)(c >> 17) * VQ_INV;
        ax += m.x * v;
        ay += m.y * v;
    }
    float2 bb = ((const float2*)bias)[lane];
    ax = fmaxf(ax + bb.x, 0.f);
    ay = fmaxf(ay + bb.y, 0.f);
    float2 M0 = ((const float2*)(M + 0 * 128))[lane];
    float2 M1 = ((const float2*)(M + 1 * 128))[lane];
    float2 M2 = ((const float2*)(M + 2 * 128))[lane];
    float d = wave_sum64(ax * M0.x + ay * M0.y);
    float u = wave_sum64(ax * M1.x + ay * M1.y);
    float w = wave_sum64(ax * M2.x + ay * M2.y);
    if (lane == 0) T[wid] = make_float4(d, u, w, 0.f);
}

// ------- layer-2 scalar SpMM (packed 4B records) + gate ----------------------
__global__ __launch_bounds__(256) void gate_k(
    const int* __restrict__ rp2, const unsigned int* __restrict__ csr,
    const float4* __restrict__ To, const float4* __restrict__ Ts,
    const float* __restrict__ beta,
    float* __restrict__ a, float* __restrict__ b, int n) {
    int i = blockIdx.x * 256 + threadIdx.x;
    if (i >= n) return;
    float d1 = 0.f, u1 = 0.f, w1 = 0.f;
    {
        int e = rp2[i], end = rp2[i + 1];
        for (; e + 3 < end; e += 4) {
            unsigned int c0 = csr[e], c1 = csr[e + 1], c2 = csr[e + 2], c3 = csr[e + 3];
            float4 t0 = To[c0 & 0x1FFFF];
            float4 t1 = To[c1 & 0x1FFFF];
            float4 t2 = To[c2 & 0x1FFFF];
            float4 t3 = To[c3 & 0x1FFFF];
            float v0 = (float)(c0 >> 17) * VQ_INV, v1 = (float)(c1 >> 17) * VQ_INV;
            float v2 = (float)(c2 >> 17) * VQ_INV, v3 = (float)(c3 >> 17) * VQ_INV;
            d1 += t0.x * v0 + t1.x * v1 + t2.x * v2 + t3.x * v3;
            u1 += t0.y * v0 + t1.y * v1 + t2.y * v2 + t3.y * v3;
            w1 += t0.z * v0 + t1.z * v1 + t2.z * v2 + t3.z * v3;
        }
        for (; e < end; ++e) {
            unsigned int c = csr[e];
            float4 t = To[c & 0x1FFFF];
            float v = (float)(c >> 17) * VQ_INV;
            d1 += t.x * v; u1 += t.y * v; w1 += t.z * v;
        }
    }
    float d2 = 0.f, u2 = 0.f, w2 = 0.f;
    {
        int e = rp2[n + i], end = rp2[n + i + 1];
        for (; e + 3 < end; e += 4) {
            unsigned int c0 = csr[e], c1 = csr[e + 1], c2 = csr[e + 2], c3 = csr[e + 3];
            float4 t0 = Ts[c0 & 0x1FFFF];
            float4 t1 = Ts[c1 & 0x1FFFF];
            float4 t2 = Ts[c2 & 0x1FFFF];
            float4 t3 = Ts[c3 & 0x1FFFF];
            float v0 = (float)(c0 >> 17) * VQ_INV, v1 = (float)(c1 >> 17) * VQ_INV;
            float v2 = (float)(c2 >> 17) * VQ_INV, v3 = (float)(c3 >> 17) * VQ_INV;
            d2 += t0.x * v0 + t1.x * v1 + t2.x * v2 + t3.x * v3;
            u2 += t0.y * v0 + t1.y * v1 + t2.y * v2 + t3.y * v3;
            w2 += t0.z * v0 + t1.z * v1 + t2.z * v2 + t3.z * v3;
        }
        for (; e < end; ++e) {
            unsigned int c = csr[e];
            float4 t = Ts[c & 0x1FFFF];
            float v = (float)(c >> 17) * VQ_INV;
            d2 += t.x * v; u2 += t.y * v; w2 += t.z * v;
        }
    }
    d1 += beta[0]; u1 += beta[1]; w1 += beta[2];
    d2 += beta[4]; u2 += beta[5]; w2 += beta[6];
    a[i] = d1 * u1 + d2 * u2;
    b[i] = d1 * w1 + d2 * w2;
}

__global__ __launch_bounds__(256) void decode_k(const int* __restrict__ idx,
                                                const float* __restrict__ a,
                                                const float* __restrict__ b,
                                                const float* __restrict__ c,
                                                float* __restrict__ out, int P) {
    int i = blockIdx.x * 256 + threadIdx.x;
    if (i >= P) return;
    out[i] = a[idx[i]] + b[idx[P + i]] + *c;
}

// ---------------------------------------------------------------------------

extern "C" void kernel_launch(void* const* d_in, const int* in_sizes, int n_in,
                              void* d_out, int out_size, void* d_ws, size_t ws_size,
                              hipStream_t stream) {
    const float* x      = (const float*)d_in[0];
    const int*   o_edges= (const int*)d_in[1];
    const float* o_vals = (const float*)d_in[2];
    const int*   s_edges= (const int*)d_in[3];
    const float* s_vals = (const float*)d_in[4];
    const int*   idx    = (const int*)d_in[5];
    const float* W_o1   = (const float*)d_in[6];
    const float* b_o1   = (const float*)d_in[7];
    const float* W_o2   = (const float*)d_in[8];
    const float* b_o2   = (const float*)d_in[9];
    const float* W_s1   = (const float*)d_in[10];
    const float* b_s1   = (const float*)d_in[11];
    const float* W_s2   = (const float*)d_in[12];
    const float* b_s2   = (const float*)d_in[13];
    const float* ag1    = (const float*)d_in[14];
    const float* ag2    = (const float*)d_in[15];
    const float* dec1_W = (const float*)d_in[16];
    const float* dec1_b = (const float*)d_in[17];
    const float* dec2_W = (const float*)d_in[18];
    const float* dec2_b = (const float*)d_in[19];
    float* out = (float*)d_out;

    const int N = in_sizes[0] / 128;
    const int E = in_sizes[1] / 2;
    const int P = out_size;
    const int n2 = 2 * N;
    const int nb = (n2 + BKT_NODES - 1) / BKT_NODES;  // 1563 for N=100k

    const size_t NBH = (size_t)N * 128 * 2;  // [N,128] bf16 bytes

    char* ws = (char*)d_ws;
    size_t off = 0;
    auto alloc = [&](size_t bytes) {
        char* p = ws + off;
        off += (bytes + 255) & ~(size_t)255;
        return p;
    };

    unsigned short* B0 = (unsigned short*)alloc(NBH);  // S1o (bf16)
    unsigned short* B1 = (unsigned short*)alloc(NBH);  // S1s (bf16)
    float4* To = (float4*)alloc((size_t)N * 16);
    float4* Ts = (float4*)alloc((size_t)N * 16);
    float* av = (float*)alloc((size_t)P * 4);
    float* bv = (float*)alloc((size_t)P * 4);
    float* Mo = (float*)alloc(3 * 128 * 4);
    float* Ms = (float*)alloc(3 * 128 * 4);
    float* beta = (float*)alloc(32);
    float* cc = (float*)alloc(16);
    int* bcnt  = (int*)alloc((size_t)nb * 4);
    int* bbase = (int*)alloc((size_t)(nb + 1) * 4);
    int* bcur  = (int*)alloc((size_t)nb * 4);
    int* rp2   = (int*)alloc((size_t)(n2 + 1) * 4);
    int2* binned = (int2*)alloc((size_t)2 * E * 8);
    unsigned int* csr = (unsigned int*)alloc((size_t)2 * E * 4);  // packed 4B

    const int nblk = (N + 255) / 256;

    // ---- bucket hist + scan ----
    hipMemsetAsync(bcnt, 0, (size_t)nb * 4, stream);
    bhist_k<<<512, 256, 0, stream>>>(o_edges, s_edges, bcnt, E, N, nb);
    bscan2_k<<<1, 1024, 0, stream>>>(bcnt, bbase, bcur, nb, 2 * E);

    // ---- fat kernel: bin (first) || gemm || prep ----
    const int chunk = 2048;
    const int gblocks = (N + 127) / 128;
    const int binblocks = (2 * E + chunk - 1) / chunk;
    fused_k<<<binblocks + gblocks + 1, 256, 0, stream>>>(
        gblocks, binblocks,
        x, W_o1, W_s1, B0, B1, N,
        o_edges, o_vals, s_edges, s_vals, bcur, binned, E, N, nb, chunk,
        dec1_W, dec1_b, dec2_W, dec2_b, W_o2, b_o2, W_s2, b_s2, ag1, ag2,
        Mo, Ms, beta, cc);

    // ---- per-bucket sort -> packed csr + rp2 ----
    sort_k<<<nb, 256, 0, stream>>>(bbase, binned, csr, rp2, n2, 2 * E);

    // ---- layer-1 SpMM + bias + relu + projection to 3 scalars (both) ----
    dim3 sgrid((N * 64 + 255) / 256, 2);
    seg_spmm_fused2_k<<<sgrid, 256, 0, stream>>>(rp2, csr, B0, B1, b_o1, b_s1,
                                                 Mo, Ms, To, Ts, N);

    // ---- layer-2 scalar SpMM + gate ----
    gate_k<<<nblk, 256, 0, stream>>>(rp2, csr, To, Ts, beta, av, bv, N);

    decode_k<<<(P + 255) / 256, 256, 0, stream>>>(idx, av, bv, cc, out, P);
}

// Round 22
// 273.133 us; speedup vs baseline: 1.0422x; 1.0422x over previous
//
#include <hip/hip_runtime.h>

// ---------------------------------------------------------------------------
// IGCN link prediction, round 21 = R19 (best, 276us: chunk=8192, packed 4B
// csr) with ONE change: bin blocks dispatched FIRST in fused_k so the 391
// latency-bound bin blocks co-reside with gemm blocks from t=0 (R19 had 149
// bin blocks in a low-occupancy tail behind 782 gemm blocks).
// R20's chunk=2048 reverted: 4x more blocks = 4x the per-block fixed cost
// (LDS zero/flush of 2048 entries) -> net regression.
// ---------------------------------------------------------------------------

constexpr int BKT_SHIFT = 7;     // 128 nodes per bucket
constexpr int BKT_NODES = 128;
constexpr int SORT_CAP  = 3584;  // records/bucket (mean 2048, +34 sigma)

typedef __attribute__((ext_vector_type(8))) short bf16x8;
typedef __attribute__((ext_vector_type(4))) float f32x4;

__device__ __forceinline__ float wave_sum64(float x) {
#pragma unroll
    for (int o = 32; o > 0; o >>= 1) x += __shfl_xor(x, o, 64);
    return x;
}

__device__ __forceinline__ unsigned short f2bf(float f) {  // round-nearest-even
    unsigned int u = __float_as_uint(f);
    u += 0x7FFF + ((u >> 16) & 1);
    return (unsigned short)(u >> 16);
}

__device__ __forceinline__ float2 bf2f2(unsigned int u) {  // 2 bf16 -> 2 f32
    float2 r;
    r.x = __uint_as_float(u << 16);
    r.y = __uint_as_float(u & 0xFFFF0000u);
    return r;
}

constexpr float VQ_INV = 1.0f / 32767.0f;

// ---------------- CSR bucket build: hist + scan ----------------

__global__ __launch_bounds__(256) void bhist_k(const int* __restrict__ eo,
                                               const int* __restrict__ es,
                                               int* __restrict__ bcnt,
                                               int E, int N, int nb) {
    __shared__ int lh[2048];
    for (int i = threadIdx.x; i < nb; i += 256) lh[i] = 0;
    __syncthreads();
    int total = 2 * E;
    for (int t = blockIdx.x * 256 + threadIdx.x; t < total; t += gridDim.x * 256) {
        int g = (t >= E) ? 1 : 0;
        int e = g ? t - E : t;
        int dst = (g ? es : eo)[e];
        atomicAdd(&lh[(g * N + dst) >> BKT_SHIFT], 1);
    }
    __syncthreads();
    for (int i = threadIdx.x; i < nb; i += 256) {
        int v = lh[i];
        if (v) atomicAdd(&bcnt[i], v);
    }
}

// scan up to 2048 bucket counts (2 elems/thread) -> bases + cursors
__global__ __launch_bounds__(1024) void bscan2_k(const int* __restrict__ bcnt,
                                                 int* __restrict__ bbase,
                                                 int* __restrict__ bcur,
                                                 int nb, int total) {
    __shared__ int sh[1024];
    int t = threadIdx.x;
    int i0 = 2 * t, i1 = 2 * t + 1;
    int v0 = (i0 < nb) ? bcnt[i0] : 0;
    int v1 = (i1 < nb) ? bcnt[i1] : 0;
    int p = v0 + v1;
    sh[t] = p;
    __syncthreads();
#pragma unroll
    for (int o = 1; o < 1024; o <<= 1) {
        int tv = (t >= o) ? sh[t - o] : 0;
        __syncthreads();
        sh[t] += tv;
        __syncthreads();
    }
    int excl = sh[t] - p;
    if (i0 < nb) { bbase[i0] = excl;      bcur[i0] = excl; }
    if (i1 < nb) { bbase[i1] = excl + v0; bcur[i1] = excl + v0; }
    if (t == 0) bbase[nb] = total;
}

// ---------------- fat-kernel roles (32KB smem) ----------------

__device__ __forceinline__ void bin_role(unsigned char* smem, int bb,
                                         const int* __restrict__ eo,
                                         const float* __restrict__ vo,
                                         const int* __restrict__ es,
                                         const float* __restrict__ vs,
                                         int* __restrict__ bcur,
                                         int2* __restrict__ binned,
                                         int E, int N, int nb, int chunk) {
    int* lcnt = (int*)smem;           // 2048 ints (8KB)
    int* lbase = lcnt + 2048;         // 2048 ints (8KB)
    int c0 = bb * chunk;
    int c1 = min(c0 + chunk, 2 * E);
    for (int i = threadIdx.x; i < nb; i += 256) lcnt[i] = 0;
    __syncthreads();
    for (int t = c0 + threadIdx.x; t < c1; t += 256) {
        int g = (t >= E) ? 1 : 0;
        int e = g ? t - E : t;
        int dst = (g ? es : eo)[e];
        atomicAdd(&lcnt[(g * N + dst) >> BKT_SHIFT], 1);
    }
    __syncthreads();
    for (int i = threadIdx.x; i < nb; i += 256) {
        int v = lcnt[i];
        lbase[i] = v ? atomicAdd(&bcur[i], v) : 0;
        lcnt[i] = 0;  // reuse as local cursor
    }
    __syncthreads();
    for (int t = c0 + threadIdx.x; t < c1; t += 256) {
        int g = (t >= E) ? 1 : 0;
        int e = g ? t - E : t;
        const int* edges = g ? es : eo;
        int dst = edges[e];
        int dc = g * N + dst;
        int b = dc >> BKT_SHIFT;
        int pos = lbase[b] + atomicAdd(&lcnt[b], 1);
        int src = edges[E + e];
        float val = (g ? vs : vo)[e];
        binned[pos] = make_int2(((dc & (BKT_NODES - 1)) << 17) | src,
                                __float_as_int(val));
    }
}

// gemm role: A-frags direct from global X (f32->bf16 in regs); only WT in LDS.
__device__ __forceinline__ void gemm_role(unsigned char* smem, int blk,
                                          const float* __restrict__ X,
                                          const float* __restrict__ W0,
                                          const float* __restrict__ W1,
                                          unsigned short* __restrict__ S0,
                                          unsigned short* __restrict__ S1,
                                          int nrows) {
    unsigned short* WT = (unsigned short*)smem;  // 32 KB

    const int tid = threadIdx.x;
    const int row0 = blk * 128;
    const int w4 = (tid >> 6) * 32;
    const int lr = tid & 15;
    const int kg = (tid >> 4) & 3;

    bf16x8 a[2][4];
#pragma unroll
    for (int rt = 0; rt < 2; ++rt) {
        int gr = row0 + w4 + rt * 16 + lr;
        if (gr >= nrows) gr = nrows - 1;  // clamp; stores guarded
        const float4* Xr = (const float4*)(X + (size_t)gr * 128);
#pragma unroll
        for (int kt = 0; kt < 4; ++kt) {
            float4 v0 = Xr[(kt * 4 + kg) * 2 + 0];
            float4 v1 = Xr[(kt * 4 + kg) * 2 + 1];
            union { unsigned short h[8]; bf16x8 v; } p;
            p.h[0] = f2bf(v0.x); p.h[1] = f2bf(v0.y);
            p.h[2] = f2bf(v0.z); p.h[3] = f2bf(v0.w);
            p.h[4] = f2bf(v1.x); p.h[5] = f2bf(v1.y);
            p.h[6] = f2bf(v1.z); p.h[7] = f2bf(v1.w);
            a[rt][kt] = p.v;
        }
    }

    for (int br = 0; br < 2; ++br) {
        const float* W = br ? W1 : W0;
        unsigned short* S = br ? S1 : S0;
        if (br) __syncthreads();
        {
            int c = tid >> 1;
            int kh = (tid & 1) * 64;
#pragma unroll 8
            for (int k2 = 0; k2 < 32; ++k2) {
                int k = kh + 2 * k2;
                unsigned int lo = f2bf(W[k * 128 + c]);
                unsigned int hi = f2bf(W[(k + 1) * 128 + c]);
                int bp = (k >> 3) ^ (c & 15);
                ((unsigned int*)&WT[c * 128 + bp * 8])[(k >> 1) & 3] = lo | (hi << 16);
            }
        }
        __syncthreads();

        f32x4 acc[2][8];
#pragma unroll
        for (int rt = 0; rt < 2; ++rt)
#pragma unroll
            for (int ct = 0; ct < 8; ++ct) acc[rt][ct] = (f32x4){0.f, 0.f, 0.f, 0.f};

#pragma unroll
        for (int ct = 0; ct < 8; ++ct) {
#pragma unroll
            for (int kt = 0; kt < 4; ++kt) {
                bf16x8 b = *(const bf16x8*)&WT[(ct * 16 + lr) * 128 +
                                               (((kt * 4 + kg) ^ lr) * 8)];
                acc[0][ct] = __builtin_amdgcn_mfma_f32_16x16x32_bf16(a[0][kt], b, acc[0][ct], 0, 0, 0);
                acc[1][ct] = __builtin_amdgcn_mfma_f32_16x16x32_bf16(a[1][kt], b, acc[1][ct], 0, 0, 0);
            }
        }

#pragma unroll
        for (int rt = 0; rt < 2; ++rt)
#pragma unroll
            for (int j = 0; j < 4; ++j) {
                int gr = row0 + w4 + rt * 16 + kg * 4 + j;
                if (gr < nrows) {
                    size_t rb = (size_t)gr * 128 + lr;
#pragma unroll
                    for (int ct = 0; ct < 8; ++ct)
                        S[rb + ct * 16] = f2bf(acc[rt][ct][j]);
                }
            }
    }
}

__device__ __forceinline__ void prep_role(unsigned char* smem,
                                          const float* __restrict__ dec1_W,
                                          const float* __restrict__ dec1_b,
                                          const float* __restrict__ dec2_W,
                                          const float* __restrict__ dec2_b,
                                          const float* __restrict__ W_o2,
                                          const float* __restrict__ b_o2,
                                          const float* __restrict__ W_s2,
                                          const float* __restrict__ b_s2,
                                          const float* __restrict__ ag1,
                                          const float* __restrict__ ag2,
                                          float* __restrict__ Mo,
                                          float* __restrict__ Ms,
                                          float* __restrict__ beta,
                                          float* __restrict__ cc) {
    float* vsh = (float*)smem;  // 128 floats
    int t = threadIdx.x;
    if (t < 128) {
        float s = 0.f;
        for (int j = 0; j < 64; ++j) s += dec1_W[t * 64 + j] * dec2_W[j];
        vsh[t] = s;
    }
    __syncthreads();
    if (t < 128) {
        const float* vlo = vsh;
        const float* vhi = vsh + 64;
        float m0 = 0, m1 = 0, m2 = 0, n0 = 0, n1 = 0, n2 = 0;
        for (int k = 0; k < 64; ++k) {
            float wo = W_o2[t * 64 + k], wsv = W_s2[t * 64 + k];
            m0 += wo * ag1[k];  m1 += wo * vlo[k];  m2 += wo * vhi[k];
            n0 += wsv * ag2[k]; n1 += wsv * vlo[k]; n2 += wsv * vhi[k];
        }
        Mo[0 * 128 + t] = m0; Mo[1 * 128 + t] = m1; Mo[2 * 128 + t] = m2;
        Ms[0 * 128 + t] = n0; Ms[1 * 128 + t] = n1; Ms[2 * 128 + t] = n2;
        if (t == 0) {
            float b0 = 0, b1 = 0, b2 = 0, s0 = 0, s1 = 0, s2 = 0, c0 = 0;
            for (int k = 0; k < 64; ++k) {
                b0 += b_o2[k] * ag1[k]; b1 += b_o2[k] * vlo[k]; b2 += b_o2[k] * vhi[k];
                s0 += b_s2[k] * ag2[k]; s1 += b_s2[k] * vlo[k]; s2 += b_s2[k] * vhi[k];
                c0 += dec1_b[k] * dec2_W[k];
            }
            beta[0] = b0; beta[1] = b1; beta[2] = b2;
            beta[4] = s0; beta[5] = s1; beta[6] = s2;
            *cc = c0 + dec2_b[0];
        }
    }
}

// fat kernel: BIN blocks first | gemm blocks | prep block (chunk=8192)
__global__ __launch_bounds__(256) void fused_k(
    int gblocks, int binblocks,
    const float* __restrict__ X, const float* __restrict__ W0,
    const float* __restrict__ W1, unsigned short* __restrict__ S0,
    unsigned short* __restrict__ S1, int nrows,
    const int* __restrict__ eo, const float* __restrict__ vo,
    const int* __restrict__ es, const float* __restrict__ vs,
    int* __restrict__ bcur, int2* __restrict__ binned,
    int E, int N, int nb, int chunk,
    const float* __restrict__ dec1_W, const float* __restrict__ dec1_b,
    const float* __restrict__ dec2_W, const float* __restrict__ dec2_b,
    const float* __restrict__ W_o2, const float* __restrict__ b_o2,
    const float* __restrict__ W_s2, const float* __restrict__ b_s2,
    const float* __restrict__ ag1, const float* __restrict__ ag2,
    float* __restrict__ Mo, float* __restrict__ Ms,
    float* __restrict__ beta, float* __restrict__ cc) {
    __shared__ __align__(16) unsigned char smem[32 * 1024];
    int bid = blockIdx.x;
    if (bid < binblocks) {
        bin_role(smem, bid, eo, vo, es, vs, bcur, binned, E, N, nb, chunk);
    } else if (bid < binblocks + gblocks) {
        gemm_role(smem, bid - binblocks, X, W0, W1, S0, S1, nrows);
    } else {
        prep_role(smem, dec1_W, dec1_b, dec2_W, dec2_b, W_o2, b_o2, W_s2, b_s2,
                  ag1, ag2, Mo, Ms, beta, cc);
    }
}

// ------ per-bucket sort: emits PACKED 4B csr records (q15<<17 | src) --------

__global__ __launch_bounds__(256) void sort_k(const int* __restrict__ bbase,
                                              const int2* __restrict__ binned,
                                              unsigned int* __restrict__ csr,
                                              int* __restrict__ rp2,
                                              int n2, int total) {
    __shared__ int2 lrec[SORT_CAP];
    __shared__ int ldeg[BKT_NODES];
    __shared__ int lsc[BKT_NODES];
    int b = blockIdx.x;
    int base = bbase[b];
    int count = min(bbase[b + 1] - base, SORT_CAP);
    int tid = threadIdx.x;
    for (int k = tid; k < count; k += 256) lrec[k] = binned[base + k];
    if (tid < BKT_NODES) ldeg[tid] = 0;
    __syncthreads();
    for (int k = tid; k < count; k += 256) atomicAdd(&ldeg[lrec[k].x >> 17], 1);
    __syncthreads();
    int v = 0;
    if (tid < BKT_NODES) {
        v = ldeg[tid];
        lsc[tid] = v;
    }
    __syncthreads();
#pragma unroll
    for (int o = 1; o < BKT_NODES; o <<= 1) {
        int tv = 0;
        if (tid < BKT_NODES) tv = (tid >= o) ? lsc[tid - o] : 0;
        __syncthreads();
        if (tid < BKT_NODES) lsc[tid] += tv;
        __syncthreads();
    }
    if (tid < BKT_NODES) {
        int excl = lsc[tid] - v;
        int node = b * BKT_NODES + tid;
        if (node < n2) rp2[node] = base + excl;
        ldeg[tid] = excl;  // reuse as scatter cursor
    }
    if (b == 0 && tid == 0) rp2[n2] = total;
    __syncthreads();
    for (int k = tid; k < count; k += 256) {
        int2 r = lrec[k];
        int dl = r.x >> 17;
        int p = atomicAdd(&ldeg[dl], 1);
        float val = __int_as_float(r.y);
        unsigned int q = (unsigned int)__float2uint_rn(val * 32767.0f);
        csr[base + p] = (q << 17) | (unsigned int)(r.x & 0x1FFFF);
    }
}

// ------- layer-1 gather SpMM (bf16 rows, packed 4B records) ------------------
__global__ __launch_bounds__(256) void seg_spmm_fused2_k(
    const int* __restrict__ rp2, const unsigned int* __restrict__ csr,
    const unsigned short* __restrict__ So, const unsigned short* __restrict__ Ss,
    const float* __restrict__ bias_o, const float* __restrict__ bias_s,
    const float* __restrict__ Mo, const float* __restrict__ Ms,
    float4* __restrict__ To, float4* __restrict__ Ts, int n) {
    const int* rp;
    const unsigned int* S;
    const float* bias;
    const float* M;
    float4* T;
    if (blockIdx.y == 0) {
        rp = rp2;     S = (const unsigned int*)So; bias = bias_o; M = Mo; T = To;
    } else {
        rp = rp2 + n; S = (const unsigned int*)Ss; bias = bias_s; M = Ms; T = Ts;
    }
    int wid = (blockIdx.x * 256 + threadIdx.x) >> 6;
    int lane = threadIdx.x & 63;
    if (wid >= n) return;
    int e = rp[wid], end = rp[wid + 1];
    float ax = 0.f, ay = 0.f;
    for (; e + 7 < end; e += 8) {
        unsigned int c0 = csr[e],     c1 = csr[e + 1], c2 = csr[e + 2], c3 = csr[e + 3];
        unsigned int c4 = csr[e + 4], c5 = csr[e + 5], c6 = csr[e + 6], c7 = csr[e + 7];
        float2 m0 = bf2f2(S[(c0 & 0x1FFFF) * 64 + lane]);
        float2 m1 = bf2f2(S[(c1 & 0x1FFFF) * 64 + lane]);
        float2 m2 = bf2f2(S[(c2 & 0x1FFFF) * 64 + lane]);
        float2 m3 = bf2f2(S[(c3 & 0x1FFFF) * 64 + lane]);
        float2 m4 = bf2f2(S[(c4 & 0x1FFFF) * 64 + lane]);
        float2 m5 = bf2f2(S[(c5 & 0x1FFFF) * 64 + lane]);
        float2 m6 = bf2f2(S[(c6 & 0x1FFFF) * 64 + lane]);
        float2 m7 = bf2f2(S[(c7 & 0x1FFFF) * 64 + lane]);
        float v0 = (float)(c0 >> 17) * VQ_INV, v1 = (float)(c1 >> 17) * VQ_INV;
        float v2 = (float)(c2 >> 17) * VQ_INV, v3 = (float)(c3 >> 17) * VQ_INV;
        float v4 = (float)(c4 >> 17) * VQ_INV, v5 = (float)(c5 >> 17) * VQ_INV;
        float v6 = (float)(c6 >> 17) * VQ_INV, v7 = (float)(c7 >> 17) * VQ_INV;
        ax += m0.x * v0 + m1.x * v1 + m2.x * v2 + m3.x * v3;
        ay += m0.y * v0 + m1.y * v1 + m2.y * v2 + m3.y * v3;
        ax += m4.x * v4 + m5.x * v5 + m6.x * v6 + m7.x * v7;
        ay += m4.y * v4 + m5.y * v5 + m6.y * v6 + m7.y * v7;
    }
    for (; e + 3 < end; e += 4) {
        unsigned int c0 = csr[e], c1 = csr[e + 1], c2 = csr[e + 2], c3 = csr[e + 3];
        float2 m0 = bf2f2(S[(c0 & 0x1FFFF) * 64 + lane]);
        float2 m1 = bf2f2(S[(c1 & 0x1FFFF) * 64 + lane]);
        float2 m2 = bf2f2(S[(c2 & 0x1FFFF) * 64 + lane]);
        float2 m3 = bf2f2(S[(c3 & 0x1FFFF) * 64 + lane]);
        float v0 = (float)(c0 >> 17) * VQ_INV, v1 = (float)(c1 >> 17) * VQ_INV;
        float v2 = (float)(c2 >> 17) * VQ_INV, v3 = (float)(c3 >> 17) * VQ_INV;
        ax += m0.x * v0 + m1.x * v1 + m2.x * v2 + m3.x * v3;
        ay += m0.y * v0 + m1.y * v1 + m2.y * v2 + m3.y * v3;
    }
    for (; e < end; ++e) {
        unsigned int c = csr[e];
        float2 m = bf2f2(S[(c & 0x1FFFF) * 64 + lane]);
        float v = (float)(c >> 17) * VQ_INV;
        ax += m.x * v;
        ay += m.y * v;
    }
    float2 bb = ((const float2*)bias)[lane];
    ax = fmaxf(ax + bb.x, 0.f);
    ay = fmaxf(ay + bb.y, 0.f);
    float2 M0 = ((const float2*)(M + 0 * 128))[lane];
    float2 M1 = ((const float2*)(M + 1 * 128))[lane];
    float2 M2 = ((const float2*)(M + 2 * 128))[lane];
    float d = wave_sum64(ax * M0.x + ay * M0.y);
    float u = wave_sum64(ax * M1.x + ay * M1.y);
    float w = wave_sum64(ax * M2.x + ay * M2.y);
    if (lane == 0) T[wid] = make_float4(d, u, w, 0.f);
}

// ------- layer-2 scalar SpMM (packed 4B records) + gate ----------------------
__global__ __launch_bounds__(256) void gate_k(
    const int* __restrict__ rp2, const unsigned int* __restrict__ csr,
    const float4* __restrict__ To, const float4* __restrict__ Ts,
    const float* __restrict__ beta,
    float* __restrict__ a, float* __restrict__ b, int n) {
    int i = blockIdx.x * 256 + threadIdx.x;
    if (i >= n) return;
    float d1 = 0.f, u1 = 0.f, w1 = 0.f;
    {
        int e = rp2[i], end = rp2[i + 1];
        for (; e + 3 < end; e += 4) {
            unsigned int c0 = csr[e], c1 = csr[e + 1], c2 = csr[e + 2], c3 = csr[e + 3];
            float4 t0 = To[c0 & 0x1FFFF];
            float4 t1 = To[c1 & 0x1FFFF];
            float4 t2 = To[c2 & 0x1FFFF];
            float4 t3 = To[c3 & 0x1FFFF];
            float v0 = (float)(c0 >> 17) * VQ_INV, v1 = (float)(c1 >> 17) * VQ_INV;
            float v2 = (float)(c2 >> 17) * VQ_INV, v3 = (float)(c3 >> 17) * VQ_INV;
            d1 += t0.x * v0 + t1.x * v1 + t2.x * v2 + t3.x * v3;
            u1 += t0.y * v0 + t1.y * v1 + t2.y * v2 + t3.y * v3;
            w1 += t0.z * v0 + t1.z * v1 + t2.z * v2 + t3.z * v3;
        }
        for (; e < end; ++e) {
            unsigned int c = csr[e];
            float4 t = To[c & 0x1FFFF];
            float v = (float)(c >> 17) * VQ_INV;
            d1 += t.x * v; u1 += t.y * v; w1 += t.z * v;
        }
    }
    float d2 = 0.f, u2 = 0.f, w2 = 0.f;
    {
        int e = rp2[n + i], end = rp2[n + i + 1];
        for (; e + 3 < end; e += 4) {
            unsigned int c0 = csr[e], c1 = csr[e + 1], c2 = csr[e + 2], c3 = csr[e + 3];
            float4 t0 = Ts[c0 & 0x1FFFF];
            float4 t1 = Ts[c1 & 0x1FFFF];
            float4 t2 = Ts[c2 & 0x1FFFF];
            float4 t3 = Ts[c3 & 0x1FFFF];
            float v0 = (float)(c0 >> 17) * VQ_INV, v1 = (float)(c1 >> 17) * VQ_INV;
            float v2 = (float)(c2 >> 17) * VQ_INV, v3 = (float)(c3 >> 17) * VQ_INV;
            d2 += t0.x * v0 + t1.x * v1 + t2.x * v2 + t3.x * v3;
            u2 += t0.y * v0 + t1.y * v1 + t2.y * v2 + t3.y * v3;
            w2 += t0.z * v0 + t1.z * v1 + t2.z * v2 + t3.z * v3;
        }
        for (; e < end; ++e) {
            unsigned int c = csr[e];
            float4 t = Ts[c & 0x1FFFF];
            float v = (float)(c >> 17) * VQ_INV;
            d2 += t.x * v; u2 += t.y * v; w2 += t.z * v;
        }
    }
    d1 += beta[0]; u1 += beta[1]; w1 += beta[2];
    d2 += beta[4]; u2 += beta[5]; w2 += beta[6];
    a[i] = d1 * u1 + d2 * u2;
    b[i] = d1 * w1 + d2 * w2;
}

__global__ __launch_bounds__(256) void decode_k(const int* __restrict__ idx,
                                                const float* __restrict__ a,
                                                const float* __restrict__ b,
                                                const float* __restrict__ c,
                                                float* __restrict__ out, int P) {
    int i = blockIdx.x * 256 + threadIdx.x;
    if (i >= P) return;
    out[i] = a[idx[i]] + b[idx[P + i]] + *c;
}

// ---------------------------------------------------------------------------

extern "C" void kernel_launch(void* const* d_in, const int* in_sizes, int n_in,
                              void* d_out, int out_size, void* d_ws, size_t ws_size,
                              hipStream_t stream) {
    const float* x      = (const float*)d_in[0];
    const int*   o_edges= (const int*)d_in[1];
    const float* o_vals = (const float*)d_in[2];
    const int*   s_edges= (const int*)d_in[3];
    const float* s_vals = (const float*)d_in[4];
    const int*   idx    = (const int*)d_in[5];
    const float* W_o1   = (const float*)d_in[6];
    const float* b_o1   = (const float*)d_in[7];
    const float* W_o2   = (const float*)d_in[8];
    const float* b_o2   = (const float*)d_in[9];
    const float* W_s1   = (const float*)d_in[10];
    const float* b_s1   = (const float*)d_in[11];
    const float* W_s2   = (const float*)d_in[12];
    const float* b_s2   = (const float*)d_in[13];
    const float* ag1    = (const float*)d_in[14];
    const float* ag2    = (const float*)d_in[15];
    const float* dec1_W = (const float*)d_in[16];
    const float* dec1_b = (const float*)d_in[17];
    const float* dec2_W = (const float*)d_in[18];
    const float* dec2_b = (const float*)d_in[19];
    float* out = (float*)d_out;

    const int N = in_sizes[0] / 128;
    const int E = in_sizes[1] / 2;
    const int P = out_size;
    const int n2 = 2 * N;
    const int nb = (n2 + BKT_NODES - 1) / BKT_NODES;  // 1563 for N=100k

    const size_t NBH = (size_t)N * 128 * 2;  // [N,128] bf16 bytes

    char* ws = (char*)d_ws;
    size_t off = 0;
    auto alloc = [&](size_t bytes) {
        char* p = ws + off;
        off += (bytes + 255) & ~(size_t)255;
        return p;
    };

    unsigned short* B0 = (unsigned short*)alloc(NBH);  // S1o (bf16)
    unsigned short* B1 = (unsigned short*)alloc(NBH);  // S1s (bf16)
    float4* To = (float4*)alloc((size_t)N * 16);
    float4* Ts = (float4*)alloc((size_t)N * 16);
    float* av = (float*)alloc((size_t)P * 4);
    float* bv = (float*)alloc((size_t)P * 4);
    float* Mo = (float*)alloc(3 * 128 * 4);
    float* Ms = (float*)alloc(3 * 128 * 4);
    float* beta = (float*)alloc(32);
    float* cc = (float*)alloc(16);
    int* bcnt  = (int*)alloc((size_t)nb * 4);
    int* bbase = (int*)alloc((size_t)(nb + 1) * 4);
    int* bcur  = (int*)alloc((size_t)nb * 4);
    int* rp2   = (int*)alloc((size_t)(n2 + 1) * 4);
    int2* binned = (int2*)alloc((size_t)2 * E * 8);
    unsigned int* csr = (unsigned int*)alloc((size_t)2 * E * 4);  // packed 4B

    const int nblk = (N + 255) / 256;

    // ---- bucket hist + scan ----
    hipMemsetAsync(bcnt, 0, (size_t)nb * 4, stream);
    bhist_k<<<512, 256, 0, stream>>>(o_edges, s_edges, bcnt, E, N, nb);
    bscan2_k<<<1, 1024, 0, stream>>>(bcnt, bbase, bcur, nb, 2 * E);

    // ---- fat kernel: bin (first) || gemm || prep (chunk=8192) ----
    const int chunk = 8192;
    const int gblocks = (N + 127) / 128;
    const int binblocks = (2 * E + chunk - 1) / chunk;
    fused_k<<<binblocks + gblocks + 1, 256, 0, stream>>>(
        gblocks, binblocks,
        x, W_o1, W_s1, B0, B1, N,
        o_edges, o_vals, s_edges, s_vals, bcur, binned, E, N, nb, chunk,
        dec1_W, dec1_b, dec2_W, dec2_b, W_o2, b_o2, W_s2, b_s2, ag1, ag2,
        Mo, Ms, beta, cc);

    // ---- per-bucket sort -> packed csr + rp2 ----
    sort_k<<<nb, 256, 0, stream>>>(bbase, binned, csr, rp2, n2, 2 * E);

    // ---- layer-1 SpMM + bias + relu + projection to 3 scalars (both) ----
    dim3 sgrid((N * 64 + 255) / 256, 2);
    seg_spmm_fused2_k<<<sgrid, 256, 0, stream>>>(rp2, csr, B0, B1, b_o1, b_s1,
                                                 Mo, Ms, To, Ts, N);

    // ---- layer-2 scalar SpMM + gate ----
    gate_k<<<nblk, 256, 0, stream>>>(rp2, csr, To, Ts, beta, av, bv, N);

    decode_k<<<(P + 255) / 256, 256, 0, stream>>>(idx, av, bv, cc, out, P);
}